// Round 1
// baseline (708.600 us; speedup 1.0000x reference)
//
#include <hip/hip_runtime.h>
#include <hip/hip_bf16.h>
#include <cstdint>

#define E_ 32
#define H_ 1024
#define I_ 512
#define G_ 8
#define NSH_ 2
#define SCALE_ 2.5f
#define NROUTED (E_ * I_)            // 16384
#define NTOT (NROUTED + I_ * NSH_)   // 17408

typedef unsigned short u16;
using bf16x8_t = __attribute__((ext_vector_type(8))) __bf16;
using f32x4_t  = __attribute__((ext_vector_type(4))) float;

__device__ __forceinline__ u16 f2bf(float x) {
  union { float f; uint32_t u; } v; v.f = x;
  uint32_t u = v.u;
  uint32_t r = (u + 0x7fffu + ((u >> 16) & 1u)) >> 16;
  return (u16)r;
}

__device__ __forceinline__ void load_lds16(const void* g, void* l) {
  __builtin_amdgcn_global_load_lds(
      (const __attribute__((address_space(1))) unsigned int*)g,
      (__attribute__((address_space(3))) unsigned int*)l,
      16, 0, 0);
}

// ---------------- f32 -> bf16 conversion (vectorized x4) ----------------
__global__ void cvt_kernel(const float* __restrict__ src, u16* __restrict__ dst, long n4) {
  long i = (long)blockIdx.x * blockDim.x + threadIdx.x;
  if (i >= n4) return;
  float4 v = ((const float4*)src)[i];
  ushort4 o;
  o.x = f2bf(v.x); o.y = f2bf(v.y); o.z = f2bf(v.z); o.w = f2bf(v.w);
  ((ushort4*)dst)[i] = o;
}

// w_down [E][H][I] + sh_down [H][2I]  ->  bd [H][NTOT] with k = e*512+i | 16384+j
__global__ void wdperm_kernel(const float* __restrict__ wd, const float* __restrict__ shd,
                              u16* __restrict__ dst) {
  long i = (long)blockIdx.x * blockDim.x + threadIdx.x;
  const long tot = (long)H_ * (NTOT / 4);
  if (i >= tot) return;
  int k4 = (int)(i % (NTOT / 4));
  int hh = (int)(i / (NTOT / 4));
  int k = k4 * 4;
  const float* s;
  if (k < NROUTED) {
    int e = k >> 9, ii = k & 511;
    s = wd + ((long)e * H_ * I_ + (long)hh * I_ + ii);
  } else {
    s = shd + (long)hh * (I_ * NSH_) + (k - NROUTED);
  }
  float4 v = *(const float4*)s;
  ushort4 o;
  o.x = f2bf(v.x); o.y = f2bf(v.y); o.z = f2bf(v.z); o.w = f2bf(v.w);
  *(ushort4*)(dst + (long)hh * NTOT + k) = o;
}

// ---------------- router ----------------
__global__ void router_kernel(const float* __restrict__ h, const float* __restrict__ gw,
                              const float* __restrict__ gb, float* __restrict__ combine) {
  int t = blockIdx.x;
  __shared__ float sh[H_];
  __shared__ float part[8][E_];
  __shared__ float sc[E_], scores[E_];
  int tid = threadIdx.x;
  for (int j = tid; j < H_; j += 256) sh[j] = h[(long)t * H_ + j];
  __syncthreads();
  int e = tid & 31, c = tid >> 5;
  float p = 0.f;
  const float* w = gw + (long)e * H_ + c * 128;
  const float* hh = sh + c * 128;
  #pragma unroll 8
  for (int j = 0; j < 128; ++j) p += hh[j] * w[j];
  part[c][e] = p;
  __syncthreads();
  if (tid < E_) {
    float s = 0.f;
    for (int c2 = 0; c2 < 8; ++c2) s += part[c2][tid];
    float sig = 1.f / (1.f + __expf(-s));
    scores[tid] = sig;
    sc[tid] = sig + gb[tid];
  }
  __syncthreads();
  if (tid == 0) {
    float gs[G_];
    for (int g = 0; g < G_; ++g) {
      float m1 = -1e30f, m2 = -1e30f;
      for (int j = 0; j < 4; ++j) {
        float v = sc[g * 4 + j];
        if (v > m1) { m2 = m1; m1 = v; } else if (v > m2) m2 = v;
      }
      gs[g] = m1 + m2;
    }
    bool gsel[G_] = {};
    for (int r = 0; r < 4; ++r) {
      int bi = -1; float bv = -1e30f;
      for (int g = 0; g < G_; ++g)
        if (!gsel[g] && gs[g] > bv) { bv = gs[g]; bi = g; }
      gsel[bi] = true;
    }
    float masked[E_];
    for (int e2 = 0; e2 < E_; ++e2) masked[e2] = gsel[e2 >> 2] ? sc[e2] : 0.f;
    bool used[E_] = {};
    int idx[8]; float wt[8]; float wsum = 0.f;
    for (int r = 0; r < 8; ++r) {
      int bi = -1; float bv = -1e30f;
      for (int e2 = 0; e2 < E_; ++e2)
        if (!used[e2] && masked[e2] > bv) { bv = masked[e2]; bi = e2; }
      used[bi] = true; idx[r] = bi; wt[r] = scores[bi]; wsum += wt[r];
    }
    float inv = SCALE_ / (wsum + 1e-20f);
    float row[E_];
    for (int e2 = 0; e2 < E_; ++e2) row[e2] = 0.f;
    for (int r = 0; r < 8; ++r) row[idx[r]] = wt[r] * inv;
    for (int e2 = 0; e2 < E_; ++e2) combine[(long)t * E_ + e2] = row[e2];
  }
}

// ---------------- GEMM (B^T input, bf16 MFMA 16x16x32) ----------------
// block = 256 threads = 4 waves (2x2). Wave sub-tile = (FM*16) x (FN*16).
// Block tile = (2*FM*16) x (2*FN*16). BK = 64.
template <int FM, int FN, bool DUAL>
__global__ __launch_bounds__(256, 2) void moe_gemm(
    const u16* __restrict__ A,   // [M][K] bf16
    const u16* __restrict__ B0,  // [N][K] bf16
    const u16* __restrict__ B1,  // [N][K] bf16 (DUAL)
    const float* __restrict__ combine,  // [M][E] (DUAL epilogue)
    u16* __restrict__ outB,      // DUAL: [M][NTOT] bf16
    float* __restrict__ outF,    // !DUAL: [M][ldo] f32
    int K, int ldo) {
  constexpr int BM = FM * 32;
  constexpr int BN = FN * 32;
  __shared__ u16 lsA[BM * 64];
  __shared__ u16 lsB0[BN * 64];
  __shared__ u16 lsB1[DUAL ? BN * 64 : 16];

  const int tid = threadIdx.x;
  const int w = tid >> 6, l = tid & 63;
  const int wr = w >> 1, wc = w & 1;
  const int mBase = blockIdx.y * BM;
  const int nBase = blockIdx.x * BN;
  const int lr = l & 15, lh = l >> 4;

  f32x4_t acc0[FM][FN];
  f32x4_t acc1[FM][FN];
  #pragma unroll
  for (int m = 0; m < FM; ++m)
    #pragma unroll
    for (int n = 0; n < FN; ++n) {
      acc0[m][n] = (f32x4_t){0.f, 0.f, 0.f, 0.f};
      acc1[m][n] = (f32x4_t){0.f, 0.f, 0.f, 0.f};
    }

  for (int k0 = 0; k0 < K; k0 += 64) {
    #pragma unroll
    for (int c = tid; c < BM * 8; c += 256) {
      int row = c >> 3, cb = c & 7;
      load_lds16(A + (size_t)(mBase + row) * K + k0 + cb * 8, (char*)lsA + c * 16);
    }
    #pragma unroll
    for (int c = tid; c < BN * 8; c += 256) {
      int row = c >> 3, cb = c & 7;
      load_lds16(B0 + (size_t)(nBase + row) * K + k0 + cb * 8, (char*)lsB0 + c * 16);
    }
    if constexpr (DUAL) {
      #pragma unroll
      for (int c = tid; c < BN * 8; c += 256) {
        int row = c >> 3, cb = c & 7;
        load_lds16(B1 + (size_t)(nBase + row) * K + k0 + cb * 8, (char*)lsB1 + c * 16);
      }
    }
    __syncthreads();
    #pragma unroll
    for (int kk = 0; kk < 64; kk += 32) {
      bf16x8_t af[FM], b0f[FN], b1f[FN];
      #pragma unroll
      for (int m = 0; m < FM; ++m)
        af[m] = *(const bf16x8_t*)(lsA + (wr * FM * 16 + m * 16 + lr) * 64 + kk + lh * 8);
      #pragma unroll
      for (int n = 0; n < FN; ++n)
        b0f[n] = *(const bf16x8_t*)(lsB0 + (wc * FN * 16 + n * 16 + lr) * 64 + kk + lh * 8);
      if constexpr (DUAL) {
        #pragma unroll
        for (int n = 0; n < FN; ++n)
          b1f[n] = *(const bf16x8_t*)(lsB1 + (wc * FN * 16 + n * 16 + lr) * 64 + kk + lh * 8);
      }
      #pragma unroll
      for (int m = 0; m < FM; ++m)
        #pragma unroll
        for (int n = 0; n < FN; ++n) {
          acc0[m][n] = __builtin_amdgcn_mfma_f32_16x16x32_bf16(af[m], b0f[n], acc0[m][n], 0, 0, 0);
          if constexpr (DUAL)
            acc1[m][n] = __builtin_amdgcn_mfma_f32_16x16x32_bf16(af[m], b1f[n], acc1[m][n], 0, 0, 0);
        }
    }
    __syncthreads();
  }

  // epilogue: C row = (lh*4 + j) [M dim], col = lr [N dim] per 16x16 fragment
  #pragma unroll
  for (int m = 0; m < FM; ++m) {
    int rowb = mBase + wr * FM * 16 + m * 16;
    #pragma unroll
    for (int n = 0; n < FN; ++n) {
      int colb = nBase + wc * FN * 16 + n * 16 + lr;
      #pragma unroll
      for (int j = 0; j < 4; ++j) {
        int t = rowb + lh * 4 + j;
        if constexpr (DUAL) {
          float gv = acc0[m][n][j], uv = acc1[m][n][j];
          float factor = (colb < NROUTED) ? combine[(long)t * E_ + (colb >> 9)] : 1.0f;
          float sv = gv / (1.f + __expf(-gv));
          outB[(size_t)t * NTOT + colb] = f2bf(sv * uv * factor);
        } else {
          outF[(size_t)t * ldo + colb] = acc0[m][n][j];
        }
      }
    }
  }
}

extern "C" void kernel_launch(void* const* d_in, const int* in_sizes, int n_in,
                              void* d_out, int out_size, void* d_ws, size_t ws_size,
                              hipStream_t stream) {
  const float* hs  = (const float*)d_in[0];
  const float* gw  = (const float*)d_in[1];
  const float* gb  = (const float*)d_in[2];
  const float* wg  = (const float*)d_in[3];
  const float* wu  = (const float*)d_in[4];
  const float* wd  = (const float*)d_in[5];
  const float* shg = (const float*)d_in[6];
  const float* shu = (const float*)d_in[7];
  const float* shd = (const float*)d_in[8];
  float* out = (float*)d_out;

  const int T = in_sizes[0] / H_;  // 2048

  char* ws = (char*)d_ws;
  size_t off = 0;
  auto alloc = [&](size_t bytes) {
    char* p = ws + off;
    off += (bytes + 255) & ~(size_t)255;
    return p;
  };
  float* combine = (float*)alloc((size_t)T * E_ * 4);
  u16* hbf = (u16*)alloc((size_t)T * H_ * 2);
  u16* bg  = (u16*)alloc((size_t)NTOT * H_ * 2);
  u16* bu  = (u16*)alloc((size_t)NTOT * H_ * 2);
  u16* bd  = (u16*)alloc((size_t)H_ * NTOT * 2);
  u16* a2  = (u16*)alloc((size_t)T * NTOT * 2);
  if (off > ws_size) return;  // workspace too small; bail visibly

  auto cvt = [&](const float* s, u16* d, long n) {
    long n4 = n / 4;
    int blocks = (int)((n4 + 255) / 256);
    hipLaunchKernelGGL(cvt_kernel, dim3(blocks), dim3(256), 0, stream, s, d, n4);
  };
  cvt(hs, hbf, (long)T * H_);
  cvt(wg, bg, (long)NROUTED * H_);
  cvt(shg, bg + (size_t)NROUTED * H_, (long)I_ * NSH_ * H_);
  cvt(wu, bu, (long)NROUTED * H_);
  cvt(shu, bu + (size_t)NROUTED * H_, (long)I_ * NSH_ * H_);
  {
    long tot = (long)H_ * (NTOT / 4);
    int blocks = (int)((tot + 255) / 256);
    hipLaunchKernelGGL(wdperm_kernel, dim3(blocks), dim3(256), 0, stream, wd, shd, bd);
  }

  hipLaunchKernelGGL(router_kernel, dim3(T), dim3(256), 0, stream, hs, gw, gb, combine);

  // Phase 1: A2[t, n] = silu(h@Wg^T) * (h@Wu^T) * factor  (128x128 tile)
  hipLaunchKernelGGL((moe_gemm<4, 4, true>), dim3(NTOT / 128, T / 128), dim3(256), 0, stream,
                     hbf, bg, bu, combine, a2, (float*)nullptr, H_, 0);

  // Phase 2: out[t, h] = A2 @ bd^T   (64x128 tile, grid = 8 x 32 = 256 blocks)
  hipLaunchKernelGGL((moe_gemm<2, 4, false>), dim3(H_ / 128, T / 64), dim3(256), 0, stream,
                     a2, bd, (const u16*)nullptr, (const float*)nullptr,
                     (u16*)nullptr, out, NTOT, H_);
}

// Round 2
// 451.817 us; speedup vs baseline: 1.5683x; 1.5683x over previous
//
#include <hip/hip_runtime.h>
#include <hip/hip_bf16.h>
#include <cstdint>

#define E_ 32
#define H_ 1024
#define I_ 512
#define G_ 8
#define NSH_ 2
#define SCALE_ 2.5f
#define NROUTED (E_ * I_)            // 16384
#define NTOT (NROUTED + I_ * NSH_)   // 17408
#define PADCAP (16384 + E_ * 128)    // 20480 padded pair capacity (T=2048)

typedef unsigned short u16;
using bf16x8_t = __attribute__((ext_vector_type(8))) __bf16;
using f32x4_t  = __attribute__((ext_vector_type(4))) float;

__device__ __forceinline__ u16 f2bf(float x) {
  union { float f; uint32_t u; } v; v.f = x;
  uint32_t u = v.u;
  uint32_t r = (u + 0x7fffu + ((u >> 16) & 1u)) >> 16;
  return (u16)r;
}
__device__ __forceinline__ float bf2f(u16 x) {
  union { uint32_t u; float f; } v; v.u = ((uint32_t)x) << 16; return v.f;
}

__device__ __forceinline__ void load_lds16(const void* g, void* l) {
  __builtin_amdgcn_global_load_lds(
      (const __attribute__((address_space(1))) unsigned int*)g,
      (__attribute__((address_space(3))) unsigned int*)l,
      16, 0, 0);
}

// ---------------- f32 -> bf16 conversion (vectorized x4) ----------------
__global__ void cvt_kernel(const float* __restrict__ src, u16* __restrict__ dst, long n4) {
  long i = (long)blockIdx.x * blockDim.x + threadIdx.x;
  if (i >= n4) return;
  float4 v = ((const float4*)src)[i];
  ushort4 o;
  o.x = f2bf(v.x); o.y = f2bf(v.y); o.z = f2bf(v.z); o.w = f2bf(v.w);
  ((ushort4*)dst)[i] = o;
}

// ---------------- init: zero counters + lists ----------------
__global__ void init_kernel(int* __restrict__ counts, int* __restrict__ cursor,
                            int* __restrict__ tok_list, float* __restrict__ wt_list) {
  int i = blockIdx.x * blockDim.x + threadIdx.x;
  if (i < PADCAP) { tok_list[i] = 0; wt_list[i] = 0.f; }
  if (i < E_) { counts[i] = 0; cursor[i] = 0; }
}

// ---------------- router ----------------
__global__ void router_kernel(const float* __restrict__ h, const float* __restrict__ gw,
                              const float* __restrict__ gb, int* __restrict__ idx8,
                              float* __restrict__ wt8, int* __restrict__ counts) {
  int t = blockIdx.x;
  __shared__ float sh[H_];
  __shared__ float part[8][E_];
  __shared__ float sc[E_], scores[E_];
  int tid = threadIdx.x;
  for (int j = tid; j < H_; j += 256) sh[j] = h[(long)t * H_ + j];
  __syncthreads();
  int e = tid & 31, c = tid >> 5;
  float p = 0.f;
  const float* w = gw + (long)e * H_ + c * 128;
  const float* hh = sh + c * 128;
  #pragma unroll 8
  for (int j = 0; j < 128; ++j) p += hh[j] * w[j];
  part[c][e] = p;
  __syncthreads();
  if (tid < E_) {
    float s = 0.f;
    for (int c2 = 0; c2 < 8; ++c2) s += part[c2][tid];
    float sig = 1.f / (1.f + __expf(-s));
    scores[tid] = sig;
    sc[tid] = sig + gb[tid];
  }
  __syncthreads();
  if (tid == 0) {
    float gs[G_];
    for (int g = 0; g < G_; ++g) {
      float m1 = -1e30f, m2 = -1e30f;
      for (int j = 0; j < 4; ++j) {
        float v = sc[g * 4 + j];
        if (v > m1) { m2 = m1; m1 = v; } else if (v > m2) m2 = v;
      }
      gs[g] = m1 + m2;
    }
    bool gsel[G_] = {};
    for (int r = 0; r < 4; ++r) {
      int bi = -1; float bv = -1e30f;
      for (int g = 0; g < G_; ++g)
        if (!gsel[g] && gs[g] > bv) { bv = gs[g]; bi = g; }
      gsel[bi] = true;
    }
    float masked[E_];
    for (int e2 = 0; e2 < E_; ++e2) masked[e2] = gsel[e2 >> 2] ? sc[e2] : 0.f;
    bool used[E_] = {};
    int idx[8]; float wt[8]; float wsum = 0.f;
    for (int r = 0; r < 8; ++r) {
      int bi = -1; float bv = -1e30f;
      for (int e2 = 0; e2 < E_; ++e2)
        if (!used[e2] && masked[e2] > bv) { bv = masked[e2]; bi = e2; }
      used[bi] = true; idx[r] = bi; wt[r] = scores[bi]; wsum += wt[r];
    }
    float inv = SCALE_ / (wsum + 1e-20f);
    for (int r = 0; r < 8; ++r) {
      idx8[(long)t * 8 + r] = idx[r];
      wt8[(long)t * 8 + r] = wt[r] * inv;
      atomicAdd(&counts[idx[r]], 1);
    }
  }
}

// ---------------- scan (padded offsets) ----------------
__global__ void scan_kernel(const int* __restrict__ counts, int* __restrict__ offs) {
  if (threadIdx.x == 0 && blockIdx.x == 0) {
    int run = 0;
    for (int e = 0; e < E_; ++e) {
      offs[e] = run;
      run += ((counts[e] + 127) >> 7) << 7;
    }
    offs[E_] = run;
  }
}

// ---------------- fill per-expert lists ----------------
__global__ void fill_kernel(const int* __restrict__ idx8, const float* __restrict__ wt8,
                            const int* __restrict__ offs, int* __restrict__ cursor,
                            int* __restrict__ tok_list, float* __restrict__ wt_list,
                            int* __restrict__ pair_pos, int npair) {
  int i = blockIdx.x * blockDim.x + threadIdx.x;
  if (i >= npair) return;
  int e = idx8[i];
  int p = atomicAdd(&cursor[e], 1);
  int slot = offs[e] + p;
  tok_list[slot] = i >> 3;
  wt_list[slot] = wt8[i];
  pair_pos[i] = slot;
}

// ---------------- phase 1: gathered dual GEMM (gate+up) ----------------
// block tile: 128 tokens x 128 I-cols, K=1024, BK=64. 4 waves (2x2), FM=FN=4.
__global__ __launch_bounds__(256, 2) void p1_kernel(
    const u16* __restrict__ hbf,   // [T][H]
    const u16* __restrict__ bg,    // [NTOT][H]
    const u16* __restrict__ bu,    // [NTOT][H]
    const int* __restrict__ counts, const int* __restrict__ offs,
    const int* __restrict__ tok_list, const float* __restrict__ wt_list,
    u16* __restrict__ gu,          // [PADCAP][512]
    u16* __restrict__ gu_sh,       // [T][1024]
    int T) {
  const int z = blockIdx.z;            // 0..E_-1 routed, E_ = shared
  const int tt = blockIdx.y;
  const int nb = blockIdx.x;
  const bool shared = (z == E_);
  if (!shared && nb >= 4) return;
  const int cnt = shared ? T : counts[z];
  if (tt * 128 >= cnt) return;
  const int off = shared ? 0 : offs[z];

  __shared__ u16 lsA[128 * 64];
  __shared__ u16 lsB0[128 * 64];
  __shared__ u16 lsB1[128 * 64];
  __shared__ int s_tok[128];
  __shared__ float s_wt[128];

  const int tid = threadIdx.x;
  if (tid < 128) {
    if (shared) { s_tok[tid] = tt * 128 + tid; s_wt[tid] = 1.0f; }
    else {
      int slot = off + tt * 128 + tid;
      s_tok[tid] = tok_list[slot];
      s_wt[tid] = wt_list[slot];
    }
  }
  __syncthreads();

  const int w = tid >> 6, l = tid & 63;
  const int wr = w >> 1, wc = w & 1;
  const int lr = l & 15, lh = l >> 4;

  const u16* Bg = shared ? (bg + (size_t)(NROUTED + nb * 128) * H_)
                         : (bg + ((size_t)z * I_ + nb * 128) * H_);
  const u16* Bu = shared ? (bu + (size_t)(NROUTED + nb * 128) * H_)
                         : (bu + ((size_t)z * I_ + nb * 128) * H_);

  f32x4_t acc0[4][4], acc1[4][4];
  #pragma unroll
  for (int m = 0; m < 4; ++m)
    #pragma unroll
    for (int n = 0; n < 4; ++n) {
      acc0[m][n] = (f32x4_t){0.f, 0.f, 0.f, 0.f};
      acc1[m][n] = (f32x4_t){0.f, 0.f, 0.f, 0.f};
    }

  for (int k0 = 0; k0 < H_; k0 += 64) {
    #pragma unroll
    for (int c = tid; c < 128 * 8; c += 256) {
      int row = c >> 3, cb = c & 7;
      load_lds16(hbf + (size_t)s_tok[row] * H_ + k0 + cb * 8, (char*)lsA + c * 16);
    }
    #pragma unroll
    for (int c = tid; c < 128 * 8; c += 256) {
      int row = c >> 3, cb = c & 7;
      load_lds16(Bg + (size_t)row * H_ + k0 + cb * 8, (char*)lsB0 + c * 16);
    }
    #pragma unroll
    for (int c = tid; c < 128 * 8; c += 256) {
      int row = c >> 3, cb = c & 7;
      load_lds16(Bu + (size_t)row * H_ + k0 + cb * 8, (char*)lsB1 + c * 16);
    }
    __syncthreads();
    #pragma unroll
    for (int kk = 0; kk < 64; kk += 32) {
      bf16x8_t af[4], b0f[4], b1f[4];
      #pragma unroll
      for (int m = 0; m < 4; ++m)
        af[m] = *(const bf16x8_t*)(lsA + (wr * 64 + m * 16 + lr) * 64 + kk + lh * 8);
      #pragma unroll
      for (int n = 0; n < 4; ++n) {
        b0f[n] = *(const bf16x8_t*)(lsB0 + (wc * 64 + n * 16 + lr) * 64 + kk + lh * 8);
        b1f[n] = *(const bf16x8_t*)(lsB1 + (wc * 64 + n * 16 + lr) * 64 + kk + lh * 8);
      }
      #pragma unroll
      for (int m = 0; m < 4; ++m)
        #pragma unroll
        for (int n = 0; n < 4; ++n) {
          acc0[m][n] = __builtin_amdgcn_mfma_f32_16x16x32_bf16(af[m], b0f[n], acc0[m][n], 0, 0, 0);
          acc1[m][n] = __builtin_amdgcn_mfma_f32_16x16x32_bf16(af[m], b1f[n], acc1[m][n], 0, 0, 0);
        }
    }
    __syncthreads();
  }

  const int ldo = shared ? (I_ * NSH_) : I_;
  u16* outp = shared ? (gu_sh + (size_t)(tt * 128) * ldo + nb * 128)
                     : (gu + (size_t)(off + tt * 128) * ldo + nb * 128);
  #pragma unroll
  for (int m = 0; m < 4; ++m) {
    #pragma unroll
    for (int n = 0; n < 4; ++n) {
      int col = wc * 64 + n * 16 + lr;
      #pragma unroll
      for (int j = 0; j < 4; ++j) {
        int trow = wr * 64 + m * 16 + lh * 4 + j;
        float gv = acc0[m][n][j], uv = acc1[m][n][j];
        float sv = gv / (1.f + __expf(-gv));
        outp[(size_t)trow * ldo + col] = f2bf(sv * uv * s_wt[trow]);
      }
    }
  }
}

// ---------------- phase 2: gathered GEMM (down projection) ----------------
// block tile: 128 pairs x 128 H-cols, K=512 (routed) / 1024 (shared).
__global__ __launch_bounds__(256, 2) void p2_kernel(
    const u16* __restrict__ gu, const u16* __restrict__ gu_sh,
    const u16* __restrict__ bd,    // [E][H][I] bf16
    const u16* __restrict__ shd,   // [H][2I] bf16
    const int* __restrict__ counts, const int* __restrict__ offs,
    u16* __restrict__ part,        // [PADCAP][H]
    u16* __restrict__ part_sh,     // [T][H]
    int T) {
  const int z = blockIdx.z;
  const int tt = blockIdx.y;
  const int nb = blockIdx.x;    // 0..7 (H tiles of 128)
  const bool shared = (z == E_);
  const int cnt = shared ? T : counts[z];
  if (tt * 128 >= cnt) return;

  __shared__ u16 lsA[128 * 64];
  __shared__ u16 lsB[128 * 64];

  const int tid = threadIdx.x;
  const int w = tid >> 6, l = tid & 63;
  const int wr = w >> 1, wc = w & 1;
  const int lr = l & 15, lh = l >> 4;

  const int K = shared ? (I_ * NSH_) : I_;
  const u16* Ab = shared ? (gu_sh + (size_t)(tt * 128) * K)
                         : (gu + (size_t)(offs[z] + tt * 128) * K);
  const u16* Bb = shared ? (shd + (size_t)(nb * 128) * K)
                         : (bd + ((size_t)z * H_ + nb * 128) * K);
  u16* outp = shared ? (part_sh + (size_t)(tt * 128) * H_ + nb * 128)
                     : (part + (size_t)(offs[z] + tt * 128) * H_ + nb * 128);

  f32x4_t acc[4][4];
  #pragma unroll
  for (int m = 0; m < 4; ++m)
    #pragma unroll
    for (int n = 0; n < 4; ++n) acc[m][n] = (f32x4_t){0.f, 0.f, 0.f, 0.f};

  for (int k0 = 0; k0 < K; k0 += 64) {
    #pragma unroll
    for (int c = tid; c < 128 * 8; c += 256) {
      int row = c >> 3, cb = c & 7;
      load_lds16(Ab + (size_t)row * K + k0 + cb * 8, (char*)lsA + c * 16);
    }
    #pragma unroll
    for (int c = tid; c < 128 * 8; c += 256) {
      int row = c >> 3, cb = c & 7;
      load_lds16(Bb + (size_t)row * K + k0 + cb * 8, (char*)lsB + c * 16);
    }
    __syncthreads();
    #pragma unroll
    for (int kk = 0; kk < 64; kk += 32) {
      bf16x8_t af[4], bf[4];
      #pragma unroll
      for (int m = 0; m < 4; ++m)
        af[m] = *(const bf16x8_t*)(lsA + (wr * 64 + m * 16 + lr) * 64 + kk + lh * 8);
      #pragma unroll
      for (int n = 0; n < 4; ++n)
        bf[n] = *(const bf16x8_t*)(lsB + (wc * 64 + n * 16 + lr) * 64 + kk + lh * 8);
      #pragma unroll
      for (int m = 0; m < 4; ++m)
        #pragma unroll
        for (int n = 0; n < 4; ++n)
          acc[m][n] = __builtin_amdgcn_mfma_f32_16x16x32_bf16(af[m], bf[n], acc[m][n], 0, 0, 0);
    }
    __syncthreads();
  }

  #pragma unroll
  for (int m = 0; m < 4; ++m) {
    #pragma unroll
    for (int n = 0; n < 4; ++n) {
      int col = wc * 64 + n * 16 + lr;
      #pragma unroll
      for (int j = 0; j < 4; ++j) {
        int trow = wr * 64 + m * 16 + lh * 4 + j;
        outp[(size_t)trow * H_ + col] = f2bf(acc[m][n][j]);
      }
    }
  }
}

// ---------------- combine ----------------
__global__ void combine_kernel(const u16* __restrict__ part, const u16* __restrict__ part_sh,
                               const int* __restrict__ pair_pos, float* __restrict__ out) {
  int t = blockIdx.x;
  int h = threadIdx.x * 4;
  int pp[8];
  #pragma unroll
  for (int s = 0; s < 8; ++s) pp[s] = pair_pos[(long)t * 8 + s];
  ushort4 v = *(const ushort4*)(part_sh + (size_t)t * H_ + h);
  float a0 = bf2f(v.x), a1 = bf2f(v.y), a2 = bf2f(v.z), a3 = bf2f(v.w);
  #pragma unroll
  for (int s = 0; s < 8; ++s) {
    ushort4 u = *(const ushort4*)(part + (size_t)pp[s] * H_ + h);
    a0 += bf2f(u.x); a1 += bf2f(u.y); a2 += bf2f(u.z); a3 += bf2f(u.w);
  }
  float4 o = {a0, a1, a2, a3};
  *(float4*)(out + (size_t)t * H_ + h) = o;
}

extern "C" void kernel_launch(void* const* d_in, const int* in_sizes, int n_in,
                              void* d_out, int out_size, void* d_ws, size_t ws_size,
                              hipStream_t stream) {
  const float* hs  = (const float*)d_in[0];
  const float* gw  = (const float*)d_in[1];
  const float* gb  = (const float*)d_in[2];
  const float* wg  = (const float*)d_in[3];
  const float* wu  = (const float*)d_in[4];
  const float* wd  = (const float*)d_in[5];
  const float* shg = (const float*)d_in[6];
  const float* shu = (const float*)d_in[7];
  const float* shd = (const float*)d_in[8];
  float* out = (float*)d_out;

  const int T = in_sizes[0] / H_;  // 2048

  char* ws = (char*)d_ws;
  size_t off = 0;
  auto alloc = [&](size_t bytes) {
    char* p = ws + off;
    off += (bytes + 255) & ~(size_t)255;
    return p;
  };
  int*   counts   = (int*)alloc(E_ * 4);
  int*   cursor   = (int*)alloc(E_ * 4);
  int*   offsv    = (int*)alloc((E_ + 1) * 4);
  int*   idx8     = (int*)alloc((size_t)T * 8 * 4);
  float* wt8      = (float*)alloc((size_t)T * 8 * 4);
  int*   pair_pos = (int*)alloc((size_t)T * 8 * 4);
  int*   tok_list = (int*)alloc(PADCAP * 4);
  float* wt_list  = (float*)alloc(PADCAP * 4);
  u16* hbf   = (u16*)alloc((size_t)T * H_ * 2);
  u16* bg    = (u16*)alloc((size_t)NTOT * H_ * 2);
  u16* bu    = (u16*)alloc((size_t)NTOT * H_ * 2);
  u16* bd    = (u16*)alloc((size_t)E_ * H_ * I_ * 2);
  u16* shdb  = (u16*)alloc((size_t)H_ * I_ * NSH_ * 2);
  u16* gu    = (u16*)alloc((size_t)PADCAP * I_ * 2);
  u16* gu_sh = (u16*)alloc((size_t)T * I_ * NSH_ * 2);
  u16* part  = (u16*)alloc((size_t)PADCAP * H_ * 2);
  u16* part_sh = (u16*)alloc((size_t)T * H_ * 2);
  if (off > ws_size) return;  // workspace too small; fail visibly

  auto cvt = [&](const float* s, u16* d, long n) {
    long n4 = n / 4;
    int blocks = (int)((n4 + 255) / 256);
    hipLaunchKernelGGL(cvt_kernel, dim3(blocks), dim3(256), 0, stream, s, d, n4);
  };

  hipLaunchKernelGGL(init_kernel, dim3((PADCAP + 255) / 256), dim3(256), 0, stream,
                     counts, cursor, tok_list, wt_list);

  cvt(hs, hbf, (long)T * H_);
  cvt(wg, bg, (long)NROUTED * H_);
  cvt(shg, bg + (size_t)NROUTED * H_, (long)I_ * NSH_ * H_);
  cvt(wu, bu, (long)NROUTED * H_);
  cvt(shu, bu + (size_t)NROUTED * H_, (long)I_ * NSH_ * H_);
  cvt(wd, bd, (long)E_ * H_ * I_);
  cvt(shd, shdb, (long)H_ * I_ * NSH_);

  hipLaunchKernelGGL(router_kernel, dim3(T), dim3(256), 0, stream, hs, gw, gb,
                     idx8, wt8, counts);
  hipLaunchKernelGGL(scan_kernel, dim3(1), dim3(64), 0, stream, counts, offsv);
  hipLaunchKernelGGL(fill_kernel, dim3((T * 8 + 255) / 256), dim3(256), 0, stream,
                     idx8, wt8, offsv, cursor, tok_list, wt_list, pair_pos, T * 8);

  hipLaunchKernelGGL(p1_kernel, dim3(8, T / 128, E_ + 1), dim3(256), 0, stream,
                     hbf, bg, bu, counts, offsv, tok_list, wt_list, gu, gu_sh, T);

  hipLaunchKernelGGL(p2_kernel, dim3(8, T / 128, E_ + 1), dim3(256), 0, stream,
                     gu, gu_sh, bd, shdb, counts, offsv, part, part_sh, T);

  hipLaunchKernelGGL(combine_kernel, dim3(T), dim3(256), 0, stream,
                     part, part_sh, pair_pos, out);
}

// Round 3
// 381.805 us; speedup vs baseline: 1.8559x; 1.1834x over previous
//
#include <hip/hip_runtime.h>
#include <hip/hip_bf16.h>
#include <cstdint>

#define E_ 32
#define H_ 1024
#define I_ 512
#define G_ 8
#define NSH_ 2
#define SCALE_ 2.5f
#define NROUTED (E_ * I_)            // 16384
#define NTOT (NROUTED + I_ * NSH_)   // 17408
#define PADCAP (16384 + E_ * 64)     // padded pair capacity (pad-to-64)

typedef unsigned short u16;
using bf16x8_t = __attribute__((ext_vector_type(8))) __bf16;
using f32x4_t  = __attribute__((ext_vector_type(4))) float;

__device__ __forceinline__ u16 f2bf(float x) {
  union { float f; uint32_t u; } v; v.f = x;
  uint32_t u = v.u;
  uint32_t r = (u + 0x7fffu + ((u >> 16) & 1u)) >> 16;
  return (u16)r;
}
__device__ __forceinline__ float bf2f(u16 x) {
  union { uint32_t u; float f; } v; v.u = ((uint32_t)x) << 16; return v.f;
}

__device__ __forceinline__ void load_lds16(const void* g, void* l) {
  __builtin_amdgcn_global_load_lds(
      (const __attribute__((address_space(1))) unsigned int*)g,
      (__attribute__((address_space(3))) unsigned int*)l,
      16, 0, 0);
}

// ---------------- f32 -> bf16 conversion (vectorized x4) ----------------
__global__ void cvt_kernel(const float* __restrict__ src, u16* __restrict__ dst, long n4) {
  long i = (long)blockIdx.x * blockDim.x + threadIdx.x;
  if (i >= n4) return;
  float4 v = ((const float4*)src)[i];
  ushort4 o;
  o.x = f2bf(v.x); o.y = f2bf(v.y); o.z = f2bf(v.z); o.w = f2bf(v.w);
  ((ushort4*)dst)[i] = o;
}

// ---------------- init ----------------
__global__ void init_kernel(int* __restrict__ counts, int* __restrict__ cursor,
                            int* __restrict__ tok_list, float* __restrict__ wt_list) {
  int i = blockIdx.x * blockDim.x + threadIdx.x;
  if (i < PADCAP) { tok_list[i] = 0; wt_list[i] = 0.f; }
  if (i < E_) { counts[i] = 0; cursor[i] = 0; }
}

// ---------------- router part a: gw [E][H] -> gwT [H][E] ----------------
__global__ void gwt_kernel(const float* __restrict__ gw, float* __restrict__ gwT) {
  int i = blockIdx.x * blockDim.x + threadIdx.x;  // i = k*32 + e
  if (i >= H_ * E_) return;
  int k = i >> 5, e = i & 31;
  gwT[i] = gw[(long)e * H_ + k];
}

// ---------------- router part b: logits = h @ gwT  (f32 exact) ----------
// block = 256 thr = 4 waves; wave owns 2 tokens (lane>>5), lane&31 = expert.
__global__ __launch_bounds__(256) void logits_kernel(
    const float* __restrict__ h, const float* __restrict__ gwT,
    float* __restrict__ logits) {
  __shared__ float sh[8][H_];   // 32 KB
  const int tid = threadIdx.x;
  const int t0 = blockIdx.x * 8;
  // cooperative load 8 rows of h (float4, coalesced)
  #pragma unroll
  for (int c = tid; c < 8 * H_ / 4; c += 256) {
    int row = c / (H_ / 4), col = c % (H_ / 4);
    ((float4*)sh[row])[col] = ((const float4*)(h + (size_t)(t0 + row) * H_))[col];
  }
  __syncthreads();
  const int w = tid >> 6, l = tid & 63;
  const int e = l & 31, tl = w * 2 + (l >> 5);
  const float* hp = sh[tl];
  const float* wp = gwT + e;
  float acc = 0.f;
  #pragma unroll 8
  for (int k = 0; k < H_; ++k) acc += hp[k] * wp[(size_t)k * E_];
  logits[(size_t)(t0 + tl) * E_ + e] = acc;
}

// ---------------- router part c: top-k selection (1 thread / token) -----
__global__ __launch_bounds__(256) void topk_kernel(
    const float* __restrict__ logits, const float* __restrict__ gb,
    int* __restrict__ idx8, float* __restrict__ wt8, int* __restrict__ counts) {
  __shared__ float s_sc[256][33];
  const int lt = threadIdx.x;
  const int t = blockIdx.x * 256 + lt;
  float sc[E_];
  #pragma unroll
  for (int e = 0; e < E_; ++e) {
    float lg = logits[(size_t)t * E_ + e];
    float sig = 1.f / (1.f + __expf(-lg));
    s_sc[lt][e] = sig;
    sc[e] = sig + gb[e];
  }
  float gs[G_];
  #pragma unroll
  for (int g = 0; g < G_; ++g) {
    float a = sc[g * 4], b = sc[g * 4 + 1], c = sc[g * 4 + 2], d = sc[g * 4 + 3];
    float hi1 = fmaxf(a, b), lo1 = fminf(a, b);
    float hi2 = fmaxf(c, d), lo2 = fminf(c, d);
    float m1 = fmaxf(hi1, hi2);
    float m2 = (hi1 >= hi2) ? fmaxf(lo1, hi2) : fmaxf(lo2, hi1);
    gs[g] = m1 + m2;
  }
  unsigned gm = 0;
  #pragma unroll
  for (int r = 0; r < 4; ++r) {
    float bv = -1e30f; int bi = 0;
    #pragma unroll
    for (int g = 0; g < G_; ++g)
      if (!(gm & (1u << g)) && gs[g] > bv) { bv = gs[g]; bi = g; }
    gm |= 1u << bi;
  }
  float msk[E_];
  #pragma unroll
  for (int e = 0; e < E_; ++e)
    msk[e] = ((gm >> (e >> 2)) & 1u) ? sc[e] : 0.f;
  unsigned um = 0; float wsum = 0.f;
  int idxs[8]; float wts[8];
  #pragma unroll
  for (int r = 0; r < 8; ++r) {
    float bv = -1e30f; int bi = 0;
    #pragma unroll
    for (int e = 0; e < E_; ++e)
      if (!(um & (1u << e)) && msk[e] > bv) { bv = msk[e]; bi = e; }
    um |= 1u << bi;
    idxs[r] = bi;
    float wv = s_sc[lt][bi];   // exact raw sigmoid
    wts[r] = wv; wsum += wv;
  }
  float inv = SCALE_ / (wsum + 1e-20f);
  #pragma unroll
  for (int r = 0; r < 8; ++r) {
    idx8[(size_t)t * 8 + r] = idxs[r];
    wt8[(size_t)t * 8 + r] = wts[r] * inv;
    atomicAdd(&counts[idxs[r]], 1);
  }
}

// ---------------- scan (pad to 64) ----------------
__global__ void scan_kernel(const int* __restrict__ counts, int* __restrict__ offs) {
  if (threadIdx.x == 0 && blockIdx.x == 0) {
    int run = 0;
    for (int e = 0; e < E_; ++e) {
      offs[e] = run;
      run += ((counts[e] + 63) >> 6) << 6;
    }
    offs[E_] = run;
  }
}

// ---------------- fill per-expert lists ----------------
__global__ void fill_kernel(const int* __restrict__ idx8, const float* __restrict__ wt8,
                            const int* __restrict__ offs, int* __restrict__ cursor,
                            int* __restrict__ tok_list, float* __restrict__ wt_list,
                            int* __restrict__ pair_pos, int npair) {
  int i = blockIdx.x * blockDim.x + threadIdx.x;
  if (i >= npair) return;
  int e = idx8[i];
  int p = atomicAdd(&cursor[e], 1);
  int slot = offs[e] + p;
  tok_list[slot] = i >> 3;
  wt_list[slot] = wt8[i];
  pair_pos[i] = slot;
}

// ---------------- phase 1: gathered dual GEMM (gate+up) ----------------
// block tile: 64 tokens x 128 I-cols, K=H, BK=64. 4 waves (2x2), FM=2, FN=4.
__global__ __launch_bounds__(256, 3) void p1_kernel(
    const u16* __restrict__ hbf,   // [T][H]
    const u16* __restrict__ bg,    // [NTOT][H]
    const u16* __restrict__ bu,    // [NTOT][H]
    const int* __restrict__ counts, const int* __restrict__ offs,
    const int* __restrict__ tok_list, const float* __restrict__ wt_list,
    u16* __restrict__ gu,          // [PADCAP][512]
    u16* __restrict__ gu_sh,       // [T][1024]
    int T) {
  const int z = blockIdx.z;            // 0..E_-1 routed, E_ = shared
  const int tt = blockIdx.y;
  const int nb = blockIdx.x;
  const bool shared = (z == E_);
  if (!shared && nb >= 4) return;
  const int cnt = shared ? T : counts[z];
  if (tt * 64 >= cnt) return;
  const int off = shared ? 0 : offs[z];

  __shared__ u16 lsA[64 * 64];
  __shared__ u16 lsB0[128 * 64];
  __shared__ u16 lsB1[128 * 64];
  __shared__ int s_tok[64];
  __shared__ float s_wt[64];

  const int tid = threadIdx.x;
  if (tid < 64) {
    if (shared) { s_tok[tid] = tt * 64 + tid; s_wt[tid] = 1.0f; }
    else {
      int slot = off + tt * 64 + tid;
      s_tok[tid] = tok_list[slot];
      s_wt[tid] = wt_list[slot];
    }
  }
  __syncthreads();

  const int w = tid >> 6, l = tid & 63;
  const int wr = w >> 1, wc = w & 1;
  const int lr = l & 15, lh = l >> 4;

  const u16* Bg = shared ? (bg + (size_t)(NROUTED + nb * 128) * H_)
                         : (bg + ((size_t)z * I_ + nb * 128) * H_);
  const u16* Bu = shared ? (bu + (size_t)(NROUTED + nb * 128) * H_)
                         : (bu + ((size_t)z * I_ + nb * 128) * H_);

  f32x4_t acc0[2][4], acc1[2][4];
  #pragma unroll
  for (int m = 0; m < 2; ++m)
    #pragma unroll
    for (int n = 0; n < 4; ++n) {
      acc0[m][n] = (f32x4_t){0.f, 0.f, 0.f, 0.f};
      acc1[m][n] = (f32x4_t){0.f, 0.f, 0.f, 0.f};
    }

  for (int k0 = 0; k0 < H_; k0 += 64) {
    #pragma unroll
    for (int c = tid; c < 64 * 8; c += 256) {
      int row = c >> 3, cb = c & 7;
      load_lds16(hbf + (size_t)s_tok[row] * H_ + k0 + cb * 8, (char*)lsA + c * 16);
    }
    #pragma unroll
    for (int c = tid; c < 128 * 8; c += 256) {
      int row = c >> 3, cb = c & 7;
      load_lds16(Bg + (size_t)row * H_ + k0 + cb * 8, (char*)lsB0 + c * 16);
    }
    #pragma unroll
    for (int c = tid; c < 128 * 8; c += 256) {
      int row = c >> 3, cb = c & 7;
      load_lds16(Bu + (size_t)row * H_ + k0 + cb * 8, (char*)lsB1 + c * 16);
    }
    __syncthreads();
    #pragma unroll
    for (int kk = 0; kk < 64; kk += 32) {
      bf16x8_t af[2], b0f[4], b1f[4];
      #pragma unroll
      for (int m = 0; m < 2; ++m)
        af[m] = *(const bf16x8_t*)(lsA + (wr * 32 + m * 16 + lr) * 64 + kk + lh * 8);
      #pragma unroll
      for (int n = 0; n < 4; ++n) {
        b0f[n] = *(const bf16x8_t*)(lsB0 + (wc * 64 + n * 16 + lr) * 64 + kk + lh * 8);
        b1f[n] = *(const bf16x8_t*)(lsB1 + (wc * 64 + n * 16 + lr) * 64 + kk + lh * 8);
      }
      #pragma unroll
      for (int m = 0; m < 2; ++m)
        #pragma unroll
        for (int n = 0; n < 4; ++n) {
          acc0[m][n] = __builtin_amdgcn_mfma_f32_16x16x32_bf16(af[m], b0f[n], acc0[m][n], 0, 0, 0);
          acc1[m][n] = __builtin_amdgcn_mfma_f32_16x16x32_bf16(af[m], b1f[n], acc1[m][n], 0, 0, 0);
        }
    }
    __syncthreads();
  }

  const int ldo = shared ? (I_ * NSH_) : I_;
  u16* outp = shared ? (gu_sh + (size_t)(tt * 64) * ldo + nb * 128)
                     : (gu + (size_t)(off + tt * 64) * ldo + nb * 128);
  #pragma unroll
  for (int m = 0; m < 2; ++m) {
    #pragma unroll
    for (int n = 0; n < 4; ++n) {
      int col = wc * 64 + n * 16 + lr;
      #pragma unroll
      for (int j = 0; j < 4; ++j) {
        int trow = wr * 32 + m * 16 + lh * 4 + j;
        float gv = acc0[m][n][j], uv = acc1[m][n][j];
        float sv = gv / (1.f + __expf(-gv));
        outp[(size_t)trow * ldo + col] = f2bf(sv * uv * s_wt[trow]);
      }
    }
  }
}

// ---------------- phase 2: gathered GEMM (down projection) ----------------
// block tile: 64 pairs x 128 H-cols, K=512 (routed) / 1024 (shared).
__global__ __launch_bounds__(256, 4) void p2_kernel(
    const u16* __restrict__ gu, const u16* __restrict__ gu_sh,
    const u16* __restrict__ bd,    // [E][H][I] bf16
    const u16* __restrict__ shd,   // [H][2I] bf16
    const int* __restrict__ counts, const int* __restrict__ offs,
    u16* __restrict__ part,        // [PADCAP][H]
    u16* __restrict__ part_sh,     // [T][H]
    int T) {
  const int z = blockIdx.z;
  const int tt = blockIdx.y;
  const int nb = blockIdx.x;    // 0..7 (H tiles of 128)
  const bool shared = (z == E_);
  const int cnt = shared ? T : counts[z];
  if (tt * 64 >= cnt) return;

  __shared__ u16 lsA[64 * 64];
  __shared__ u16 lsB[128 * 64];

  const int tid = threadIdx.x;
  const int w = tid >> 6, l = tid & 63;
  const int wr = w >> 1, wc = w & 1;
  const int lr = l & 15, lh = l >> 4;

  const int K = shared ? (I_ * NSH_) : I_;
  const u16* Ab = shared ? (gu_sh + (size_t)(tt * 64) * K)
                         : (gu + (size_t)(offs[z] + tt * 64) * K);
  const u16* Bb = shared ? (shd + (size_t)(nb * 128) * K)
                         : (bd + ((size_t)z * H_ + nb * 128) * K);
  u16* outp = shared ? (part_sh + (size_t)(tt * 64) * H_ + nb * 128)
                     : (part + (size_t)(offs[z] + tt * 64) * H_ + nb * 128);

  f32x4_t acc[2][4];
  #pragma unroll
  for (int m = 0; m < 2; ++m)
    #pragma unroll
    for (int n = 0; n < 4; ++n) acc[m][n] = (f32x4_t){0.f, 0.f, 0.f, 0.f};

  for (int k0 = 0; k0 < K; k0 += 64) {
    #pragma unroll
    for (int c = tid; c < 64 * 8; c += 256) {
      int row = c >> 3, cb = c & 7;
      load_lds16(Ab + (size_t)row * K + k0 + cb * 8, (char*)lsA + c * 16);
    }
    #pragma unroll
    for (int c = tid; c < 128 * 8; c += 256) {
      int row = c >> 3, cb = c & 7;
      load_lds16(Bb + (size_t)row * K + k0 + cb * 8, (char*)lsB + c * 16);
    }
    __syncthreads();
    #pragma unroll
    for (int kk = 0; kk < 64; kk += 32) {
      bf16x8_t af[2], bf[4];
      #pragma unroll
      for (int m = 0; m < 2; ++m)
        af[m] = *(const bf16x8_t*)(lsA + (wr * 32 + m * 16 + lr) * 64 + kk + lh * 8);
      #pragma unroll
      for (int n = 0; n < 4; ++n)
        bf[n] = *(const bf16x8_t*)(lsB + (wc * 64 + n * 16 + lr) * 64 + kk + lh * 8);
      #pragma unroll
      for (int m = 0; m < 2; ++m)
        #pragma unroll
        for (int n = 0; n < 4; ++n)
          acc[m][n] = __builtin_amdgcn_mfma_f32_16x16x32_bf16(af[m], bf[n], acc[m][n], 0, 0, 0);
    }
    __syncthreads();
  }

  #pragma unroll
  for (int m = 0; m < 2; ++m) {
    #pragma unroll
    for (int n = 0; n < 4; ++n) {
      int col = wc * 64 + n * 16 + lr;
      #pragma unroll
      for (int j = 0; j < 4; ++j) {
        int trow = wr * 32 + m * 16 + lh * 4 + j;
        outp[(size_t)trow * H_ + col] = f2bf(acc[m][n][j]);
      }
    }
  }
}

// ---------------- combine ----------------
__global__ void combine_kernel(const u16* __restrict__ part, const u16* __restrict__ part_sh,
                               const int* __restrict__ pair_pos, float* __restrict__ out) {
  int t = blockIdx.x;
  int h = threadIdx.x * 4;
  int pp[8];
  #pragma unroll
  for (int s = 0; s < 8; ++s) pp[s] = pair_pos[(long)t * 8 + s];
  ushort4 v = *(const ushort4*)(part_sh + (size_t)t * H_ + h);
  float a0 = bf2f(v.x), a1 = bf2f(v.y), a2 = bf2f(v.z), a3 = bf2f(v.w);
  #pragma unroll
  for (int s = 0; s < 8; ++s) {
    ushort4 u = *(const ushort4*)(part + (size_t)pp[s] * H_ + h);
    a0 += bf2f(u.x); a1 += bf2f(u.y); a2 += bf2f(u.z); a3 += bf2f(u.w);
  }
  float4 o = {a0, a1, a2, a3};
  *(float4*)(out + (size_t)t * H_ + h) = o;
}

extern "C" void kernel_launch(void* const* d_in, const int* in_sizes, int n_in,
                              void* d_out, int out_size, void* d_ws, size_t ws_size,
                              hipStream_t stream) {
  const float* hs  = (const float*)d_in[0];
  const float* gw  = (const float*)d_in[1];
  const float* gb  = (const float*)d_in[2];
  const float* wg  = (const float*)d_in[3];
  const float* wu  = (const float*)d_in[4];
  const float* wd  = (const float*)d_in[5];
  const float* shg = (const float*)d_in[6];
  const float* shu = (const float*)d_in[7];
  const float* shd = (const float*)d_in[8];
  float* out = (float*)d_out;

  const int T = in_sizes[0] / H_;  // 2048

  char* ws = (char*)d_ws;
  size_t off = 0;
  auto alloc = [&](size_t bytes) {
    char* p = ws + off;
    off += (bytes + 255) & ~(size_t)255;
    return p;
  };
  int*   counts   = (int*)alloc(E_ * 4);
  int*   cursor   = (int*)alloc(E_ * 4);
  int*   offsv    = (int*)alloc((E_ + 1) * 4);
  int*   idx8     = (int*)alloc((size_t)T * 8 * 4);
  float* wt8      = (float*)alloc((size_t)T * 8 * 4);
  int*   pair_pos = (int*)alloc((size_t)T * 8 * 4);
  int*   tok_list = (int*)alloc(PADCAP * 4);
  float* wt_list  = (float*)alloc(PADCAP * 4);
  float* gwT      = (float*)alloc((size_t)H_ * E_ * 4);
  float* logits   = (float*)alloc((size_t)T * E_ * 4);
  u16* hbf   = (u16*)alloc((size_t)T * H_ * 2);
  u16* bg    = (u16*)alloc((size_t)NTOT * H_ * 2);
  u16* bu    = (u16*)alloc((size_t)NTOT * H_ * 2);
  u16* bd    = (u16*)alloc((size_t)E_ * H_ * I_ * 2);
  u16* shdb  = (u16*)alloc((size_t)H_ * I_ * NSH_ * 2);
  u16* gu    = (u16*)alloc((size_t)PADCAP * I_ * 2);
  u16* gu_sh = (u16*)alloc((size_t)T * I_ * NSH_ * 2);
  u16* part  = (u16*)alloc((size_t)PADCAP * H_ * 2);
  u16* part_sh = (u16*)alloc((size_t)T * H_ * 2);
  if (off > ws_size) return;  // workspace too small; fail visibly

  auto cvt = [&](const float* s, u16* d, long n) {
    long n4 = n / 4;
    int blocks = (int)((n4 + 255) / 256);
    hipLaunchKernelGGL(cvt_kernel, dim3(blocks), dim3(256), 0, stream, s, d, n4);
  };

  hipLaunchKernelGGL(init_kernel, dim3((PADCAP + 255) / 256), dim3(256), 0, stream,
                     counts, cursor, tok_list, wt_list);

  // router pipeline (f32 exact)
  hipLaunchKernelGGL(gwt_kernel, dim3((H_ * E_ + 255) / 256), dim3(256), 0, stream, gw, gwT);
  hipLaunchKernelGGL(logits_kernel, dim3(T / 8), dim3(256), 0, stream, hs, gwT, logits);
  hipLaunchKernelGGL(topk_kernel, dim3(T / 256), dim3(256), 0, stream,
                     logits, gb, idx8, wt8, counts);
  hipLaunchKernelGGL(scan_kernel, dim3(1), dim3(64), 0, stream, counts, offsv);
  hipLaunchKernelGGL(fill_kernel, dim3((T * 8 + 255) / 256), dim3(256), 0, stream,
                     idx8, wt8, offsv, cursor, tok_list, wt_list, pair_pos, T * 8);

  // bf16 weight/activation conversion
  cvt(hs, hbf, (long)T * H_);
  cvt(wg, bg, (long)NROUTED * H_);
  cvt(shg, bg + (size_t)NROUTED * H_, (long)I_ * NSH_ * H_);
  cvt(wu, bu, (long)NROUTED * H_);
  cvt(shu, bu + (size_t)NROUTED * H_, (long)I_ * NSH_ * H_);
  cvt(wd, bd, (long)E_ * H_ * I_);
  cvt(shd, shdb, (long)H_ * I_ * NSH_);

  hipLaunchKernelGGL(p1_kernel, dim3(8, T / 64, E_ + 1), dim3(256), 0, stream,
                     hbf, bg, bu, counts, offsv, tok_list, wt_list, gu, gu_sh, T);

  hipLaunchKernelGGL(p2_kernel, dim3(8, T / 64, E_ + 1), dim3(256), 0, stream,
                     gu, gu_sh, bd, shdb, counts, offsv, part, part_sh, T);

  hipLaunchKernelGGL(combine_kernel, dim3(T), dim3(256), 0, stream,
                     part, part_sh, pair_pos, out);
}